// Round 6
// baseline (2023.903 us; speedup 1.0000x reference)
//
#include <hip/hip_runtime.h>
#include <hip/hip_fp16.h>

// ---------------------------------------------------------------------------
// Problem constants
//   S=512 tokens, WD=300, TD=100, CE=20, CH=20, H=512, LAB=50, MAXW=16
// Outputs: arc_scores (512x512) | label_scores (50x512) | char_embeds (20x512)
// ---------------------------------------------------------------------------

static __device__ __forceinline__ float sigm(float x) { return 1.f / (1.f + __expf(-x)); }
static __device__ __forceinline__ float ftanh(float x) {
    x = fminf(15.f, fmaxf(-15.f, x));
    float e = __expf(2.f * x);
    return (e - 1.f) / (e + 1.f);
}

typedef _Float16 h2_t __attribute__((ext_vector_type(2)));
typedef _Float16 h8_t __attribute__((ext_vector_type(8)));
typedef float f4_t __attribute__((ext_vector_type(4)));
union U32H2 { unsigned u; h2_t h; unsigned short s[2]; };

static __device__ __forceinline__ float dot2f(unsigned wa, unsigned hb, float c) {
#if __has_builtin(__builtin_amdgcn_fdot2)
    U32H2 a, b; a.u = wa; b.u = hb;
    return __builtin_amdgcn_fdot2(a.h, b.h, c, false);
#else
    U32H2 a, b; a.u = wa; b.u = hb;
    return c + (float)a.h[0] * (float)b.h[0] + (float)a.h[1] * (float)b.h[1];
#endif
}
static __device__ __forceinline__ unsigned short f2h16(float x) {
    return __half_as_ushort(__float2half(x));
}

// ---------------------------------------------------------------------------
// Embedding gather
// ---------------------------------------------------------------------------
__global__ void gather_k(const int* __restrict__ sentence, const int* __restrict__ tags,
                         const float* __restrict__ word_emb, const float* __restrict__ tag_emb,
                         float* __restrict__ embeds) {
    int t = blockIdx.x;
    int w = sentence[t], tg = tags[t];
    for (int j = threadIdx.x; j < 400; j += blockDim.x) {
        float v = (j < 300) ? word_emb[w * 300 + j] : tag_emb[tg * 100 + (j - 300)];
        embeds[t * 400 + j] = v;
    }
}

// ---------------------------------------------------------------------------
// fp32 GEMM tile body on caller-provided LDS: C[64x64] = A@B^T (+bias)(relu)
// smem must hold 2 * 16*65 floats (8320 B). bm/bn are tile origins.
// ---------------------------------------------------------------------------
static __device__ __forceinline__ void gemm_body_s(
    float* smemf, const float* __restrict__ A, int lda,
    const float* __restrict__ B, int ldb,
    const float* __restrict__ bias, int bias_stride,
    float* __restrict__ C, int ldc, int M, int K, int revA, int doRelu,
    int bm, int bn) {
    typedef float Row65[65];
    Row65* As = (Row65*)smemf;
    Row65* Bs = (Row65*)(smemf + 16 * 65);
    int tx = threadIdx.x & 15, ty = threadIdx.x >> 4;
    float acc[4][4] = {};
    for (int k0 = 0; k0 < K; k0 += 16) {
#pragma unroll
        for (int i = 0; i < 4; ++i) {
            int e = threadIdx.x + i * 256;
            int m = e >> 4, kk = e & 15;
            int row = bm + m; if (revA) row = M - 1 - row;
            As[kk][m] = A[(size_t)row * lda + k0 + kk];
            Bs[kk][m] = B[(size_t)(bn + m) * ldb + k0 + kk];
        }
        __syncthreads();
#pragma unroll
        for (int kk = 0; kk < 16; ++kk) {
            float a0 = As[kk][ty * 4 + 0], a1 = As[kk][ty * 4 + 1];
            float a2 = As[kk][ty * 4 + 2], a3 = As[kk][ty * 4 + 3];
            float b0 = Bs[kk][tx * 4 + 0], b1 = Bs[kk][tx * 4 + 1];
            float b2 = Bs[kk][tx * 4 + 2], b3 = Bs[kk][tx * 4 + 3];
            acc[0][0] += a0 * b0; acc[0][1] += a0 * b1; acc[0][2] += a0 * b2; acc[0][3] += a0 * b3;
            acc[1][0] += a1 * b0; acc[1][1] += a1 * b1; acc[1][2] += a1 * b2; acc[1][3] += a1 * b3;
            acc[2][0] += a2 * b0; acc[2][1] += a2 * b1; acc[2][2] += a2 * b2; acc[2][3] += a2 * b3;
            acc[3][0] += a3 * b0; acc[3][1] += a3 * b1; acc[3][2] += a3 * b2; acc[3][3] += a3 * b3;
        }
        __syncthreads();
    }
#pragma unroll
    for (int i = 0; i < 4; ++i) {
#pragma unroll
        for (int j = 0; j < 4; ++j) {
            int n = bn + tx * 4 + j;
            float v = acc[i][j];
            if (bias) v += bias[(size_t)n * bias_stride];
            if (doRelu) v = fmaxf(v, 0.f);
            C[(size_t)(bm + ty * 4 + i) * ldc + n] = v;
        }
    }
}

__global__ __launch_bounds__(256) void gemm_abT(
    const float* __restrict__ A, int lda, const float* __restrict__ B, int ldb,
    const float* __restrict__ bias, int bias_stride,
    float* __restrict__ C, int ldc, int M, int N, int K, int revA, int doRelu) {
    __shared__ float smemf[2 * 16 * 65];
    gemm_body_s(smemf, A, lda, B, ldb, bias, bias_stride, C, ldc, M, K, revA, doRelu,
                blockIdx.y * 64, blockIdx.x * 64);
}

// ---------------------------------------------------------------------------
// PREP dispatch (independent of the LSTM, runs before it):
//   blocks [0,4050)      : biaff_label_W fp32[l][h][k] -> fp16[l][k][h] transpose
//   blocks [4050,4562)   : per-word char LSTM + gram attention
//   blocks [4562,5074)   : 2 input projections (xf/xb), xproj role
// ---------------------------------------------------------------------------
__global__ __launch_bounds__(256) void prep_k(
    const float* __restrict__ BW, _Float16* __restrict__ Bh,
    const int* __restrict__ chars, const int* __restrict__ char_lengths,
    const float* __restrict__ char_emb, const float* __restrict__ att_W,
    const float* __restrict__ att_b, const float* __restrict__ cW_ih,
    const float* __restrict__ cW_hh, const float* __restrict__ cb,
    float* __restrict__ out2,
    const float* __restrict__ embeds,
    const float* __restrict__ Wf, const float* __restrict__ bf, float* __restrict__ Cf,
    const float* __restrict__ Wb, const float* __restrict__ bb, float* __restrict__ Cb) {
    __shared__ __align__(16) unsigned char smem[16384];
    int bid = blockIdx.x;
    int tid = threadIdx.x;

    if (bid < 4050) {
        // ---------------- bconv ----------------
        typedef _Float16 TsRow[68];
        TsRow* Ts = (TsRow*)smem;
        int idx = bid;
        int lb = idx / 81, rem = idx % 81;
        int h0 = (rem % 9) * 64, k0 = (rem / 9) * 64;
        const float* Bl = BW + (size_t)lb * 513 * 513;
        _Float16* BhL = Bh + (size_t)lb * 576 * 544;
        int tr = tid >> 4, tc = tid & 15;
#pragma unroll
        for (int i = 0; i < 4; ++i) {
            int hl = tr + i * 16;
            int h = h0 + hl;
#pragma unroll
            for (int j = 0; j < 4; ++j) {
                int k = k0 + tc * 4 + j;
                float v = (h < 513 && k < 513) ? Bl[(size_t)h * 513 + k] : 0.f;
                Ts[hl][tc * 4 + j] = (_Float16)v;
            }
        }
        __syncthreads();
        int cr = tid >> 2, hb = (tid & 3) * 16;
        int hg = h0 + hb;
        if (hg < 544) {
            __align__(16) _Float16 tmp[16];
#pragma unroll
            for (int j = 0; j < 16; ++j) tmp[j] = Ts[hb + j][cr];
            uint4* dst = (uint4*)(BhL + (size_t)(k0 + cr) * 544 + hg);
            dst[0] = ((const uint4*)tmp)[0];
            dst[1] = ((const uint4*)tmp)[1];
        }
    } else if (bid < 4050 + 512) {
        // ---------------- char LSTM + gram attention ----------------
        float* Wih = (float*)smem;          // 1600
        float* Whh2 = Wih + 1600;           // 1600
        float* cbs = Whh2 + 1600;           // 80
        float* attsh = cbs + 80;            // 20
        float* xsh = attsh + 20;            // 20
        float* hsh = xsh + 20;              // 20
        float* prodsh = hsh + 20;           // 20
        int wd = bid - 4050;
        for (int i = tid; i < 1600; i += 256) { Wih[i] = cW_ih[i]; Whh2[i] = cW_hh[i]; }
        for (int i = tid; i < 80; i += 256) cbs[i] = cb[i];
        if (tid < 20) { attsh[tid] = att_W[tid]; hsh[tid] = 0.f; }
        __syncthreads();

        int L = char_lengths[wd];
        float c = 0.f, accj = 0.f;
        for (int t = 0; t < 16; ++t) {
            if (tid < 20) xsh[tid] = char_emb[(size_t)chars[wd * 16 + t] * 20 + tid];
            __syncthreads();
            float hn = 0.f;
            if (tid < 20) {
                float z[4];
#pragma unroll
                for (int q = 0; q < 4; ++q) {
                    int rr = q * 20 + tid;
                    float sacc = cbs[rr];
                    for (int d = 0; d < 20; ++d)
                        sacc += Wih[rr * 20 + d] * xsh[d] + Whh2[rr * 20 + d] * hsh[d];
                    z[q] = sacc;
                }
                c = sigm(z[1]) * c + sigm(z[0]) * ftanh(z[2]);
                hn = sigm(z[3]) * ftanh(c);
            }
            __syncthreads();
            if (tid < 20) { hsh[tid] = hn; prodsh[tid] = hn * attsh[tid]; }
            __syncthreads();
            if (tid < 20 && t < L) {
                float st = 0.f;
                for (int k = 0; k < 20; ++k) st += prodsh[k];
                accj += hn * st;
            }
            __syncthreads();
        }
        if (tid < 20) out2[tid * 512 + wd] = accj + att_b[0];
    } else {
        // ---------------- xproj: xf/xb = embeds(@rev) @ W_ih^T + b ----------------
        int idx = bid - (4050 + 512);
        int z = idx >> 8, rem = idx & 255;
        int bn = (rem & 31) * 64;   // N = 2048 -> 32 tiles
        int bm = (rem >> 5) * 64;   // M = 512  -> 8 tiles
        const float* W = z ? Wb : Wf;
        const float* bias = z ? bb : bf;
        float* C = z ? Cb : Cf;
        gemm_body_s((float*)smem, embeds, 400, W, 400, bias, 1, C, 2048,
                    512, 400, z, 0, bm, bn);
    }
}

// ---------------------------------------------------------------------------
// hconv: 4 head weight matrices fp32 -> fp16 (runs after prep, before lstm;
// Wh16 overlays the then-dead embeds/P/U/V/Uh region)
// ---------------------------------------------------------------------------
__global__ void hconv_k(const float* __restrict__ hw0, const float* __restrict__ hw1,
                        const float* __restrict__ hw2, const float* __restrict__ hw3,
                        _Float16* __restrict__ Wh16) {
    size_t e0 = ((size_t)blockIdx.x * 256 + threadIdx.x) * 8;
    int mat = (int)(e0 >> 19);
    size_t off = e0 & 524287;
    const float* src = (mat == 0 ? hw0 : mat == 1 ? hw1 : mat == 2 ? hw2 : hw3) + off;
    float4 f0 = ((const float4*)src)[0];
    float4 f1 = ((const float4*)src)[1];
    __align__(16) _Float16 hv[8];
    hv[0] = (_Float16)f0.x; hv[1] = (_Float16)f0.y;
    hv[2] = (_Float16)f0.z; hv[3] = (_Float16)f0.w;
    hv[4] = (_Float16)f1.x; hv[5] = (_Float16)f1.y;
    hv[6] = (_Float16)f1.z; hv[7] = (_Float16)f1.w;
    *(uint4*)(Wh16 + e0) = *(const uint4*)hv;
}

// ---------------------------------------------------------------------------
// Recurrent biLSTM, ISOLATED dispatch (32 WGs). Wave-autonomous r5 structure
// + s_sleep backoff in the poll retry path (cuts the atomic-load storm that
// inflates exchange RTT). Protocol: (fp16|tag16)x2 packed 8B relaxed
// agent-scope atomic qwords, parity ping-pong back-pressure.
// ---------------------------------------------------------------------------
__global__ __launch_bounds__(256) void lstm_k(
    const float* __restrict__ W_hh_f, const float* __restrict__ W_hh_b,
    const float* __restrict__ xpf, const float* __restrict__ xpb,
    _Float16* __restrict__ lstmh, unsigned long long* hq) {
    int bid = blockIdx.x;
    int dir = bid >> 4, s = bid & 15;
    int tid = threadIdx.x;
    int w = tid >> 6, l = tid & 63;
    int r = l & 7;
    int dloc = w * 8 + (l >> 3);
    int col = s * 32 + dloc;
    const float* Whh = dir ? W_hh_b : W_hh_f;
    const float* xp = dir ? xpb : xpf;

    unsigned Wreg[4][32];
#pragma unroll
    for (int gate = 0; gate < 4; ++gate) {
        const float* wrow = Whh + (size_t)(gate * 512 + col) * 512 + r * 64;
#pragma unroll
        for (int u = 0; u < 32; ++u)
            Wreg[gate][u] = (unsigned)f2h16(wrow[2 * u]) |
                            ((unsigned)f2h16(wrow[2 * u + 1]) << 16);
    }

    float c = 0.f;
    unsigned long long* hbase = hq + dir * 512;
    int base_j = r * 32 + ((l >> 3) << 2);

    for (int t = 0; t < 512; ++t) {
        const float* x = xp + (size_t)t * 2048 + col;
        float x0 = x[0], x1 = x[512], x2 = x[1024], x3 = x[1536];

        unsigned long long* hin = hbase + (t & 1) * 256 + base_j;
        unsigned tg = (unsigned)t;
        unsigned long long v0, v1, v2, v3;
        for (;;) {
            v0 = __hip_atomic_load(hin + 0, __ATOMIC_RELAXED, __HIP_MEMORY_SCOPE_AGENT);
            v1 = __hip_atomic_load(hin + 1, __ATOMIC_RELAXED, __HIP_MEMORY_SCOPE_AGENT);
            v2 = __hip_atomic_load(hin + 2, __ATOMIC_RELAXED, __HIP_MEMORY_SCOPE_AGENT);
            v3 = __hip_atomic_load(hin + 3, __ATOMIC_RELAXED, __HIP_MEMORY_SCOPE_AGENT);
            bool ok = ((((unsigned)(v0 >> 16) & 0xffffu) == tg) & (((unsigned)(v0 >> 48)) == tg))
                    & ((((unsigned)(v1 >> 16) & 0xffffu) == tg) & (((unsigned)(v1 >> 48)) == tg))
                    & ((((unsigned)(v2 >> 16) & 0xffffu) == tg) & (((unsigned)(v2 >> 48)) == tg))
                    & ((((unsigned)(v3 >> 16) & 0xffffu) == tg) & (((unsigned)(v3 >> 48)) == tg));
            if (ok) break;
            __builtin_amdgcn_s_sleep(2);   // ~128 cy backoff: throttle poll storm
        }
        unsigned H0 = (unsigned)(v0 & 0xffffu) | (((unsigned)(v0 >> 32) & 0xffffu) << 16);
        unsigned H1 = (unsigned)(v1 & 0xffffu) | (((unsigned)(v1 >> 32) & 0xffffu) << 16);
        unsigned H2 = (unsigned)(v2 & 0xffffu) | (((unsigned)(v2 >> 32) & 0xffffu) << 16);
        unsigned H3 = (unsigned)(v3 & 0xffffu) | (((unsigned)(v3 >> 32) & 0xffffu) << 16);

        float a0 = 0.f, a1 = 0.f, a2 = 0.f, a3 = 0.f;
#pragma unroll
        for (int u2 = 0; u2 < 8; ++u2) {
            int src = u2 * 8 + r;
            unsigned hv;
            hv = (unsigned)__shfl((int)H0, src);
            a0 = dot2f(Wreg[0][u2 * 4 + 0], hv, a0);
            a1 = dot2f(Wreg[1][u2 * 4 + 0], hv, a1);
            a2 = dot2f(Wreg[2][u2 * 4 + 0], hv, a2);
            a3 = dot2f(Wreg[3][u2 * 4 + 0], hv, a3);
            hv = (unsigned)__shfl((int)H1, src);
            a0 = dot2f(Wreg[0][u2 * 4 + 1], hv, a0);
            a1 = dot2f(Wreg[1][u2 * 4 + 1], hv, a1);
            a2 = dot2f(Wreg[2][u2 * 4 + 1], hv, a2);
            a3 = dot2f(Wreg[3][u2 * 4 + 1], hv, a3);
            hv = (unsigned)__shfl((int)H2, src);
            a0 = dot2f(Wreg[0][u2 * 4 + 2], hv, a0);
            a1 = dot2f(Wreg[1][u2 * 4 + 2], hv, a1);
            a2 = dot2f(Wreg[2][u2 * 4 + 2], hv, a2);
            a3 = dot2f(Wreg[3][u2 * 4 + 2], hv, a3);
            hv = (unsigned)__shfl((int)H3, src);
            a0 = dot2f(Wreg[0][u2 * 4 + 3], hv, a0);
            a1 = dot2f(Wreg[1][u2 * 4 + 3], hv, a1);
            a2 = dot2f(Wreg[2][u2 * 4 + 3], hv, a2);
            a3 = dot2f(Wreg[3][u2 * 4 + 3], hv, a3);
        }
        a0 += __shfl_xor(a0, 1); a0 += __shfl_xor(a0, 2); a0 += __shfl_xor(a0, 4);
        a1 += __shfl_xor(a1, 1); a1 += __shfl_xor(a1, 2); a1 += __shfl_xor(a1, 4);
        a2 += __shfl_xor(a2, 1); a2 += __shfl_xor(a2, 2); a2 += __shfl_xor(a2, 4);
        a3 += __shfl_xor(a3, 1); a3 += __shfl_xor(a3, 2); a3 += __shfl_xor(a3, 4);

        float z0 = a0 + x0, z1 = a1 + x1, z2 = a2 + x2, z3 = a3 + x3;
        c = sigm(z1) * c + sigm(z0) * ftanh(z2);
        float hn = sigm(z3) * ftanh(c);

        unsigned tw = (unsigned)f2h16(hn) | ((unsigned)(t + 1) << 16);
        unsigned other = (unsigned)__shfl_down((int)tw, 8);
        if (r == 0) {
            int row = dir ? (511 - t) : t;
            lstmh[(size_t)row * 1024 + dir * 512 + col] = (_Float16)hn;
            if (((l >> 3) & 1) == 0) {
                unsigned long long qv = (unsigned long long)tw |
                                        ((unsigned long long)other << 32);
                __hip_atomic_store(hbase + ((t + 1) & 1) * 256 + s * 16 + w * 4 + (l >> 4),
                                   qv, __ATOMIC_RELAXED, __HIP_MEMORY_SCOPE_AGENT);
            }
        }
    }
}

// ---------------------------------------------------------------------------
// Heads MFMA: C[hd] = relu(lstmh @ Wh16[hd]^T + bias[hd]), M=N=512, K=1024
// ---------------------------------------------------------------------------
__global__ __launch_bounds__(256) void heads_mfma(
    const _Float16* __restrict__ A,     // [512][1024]
    const _Float16* __restrict__ Wh,    // [4][512][1024]
    const float* __restrict__ b0, const float* __restrict__ b1,
    const float* __restrict__ b2, const float* __restrict__ b3,
    float* __restrict__ Cout) {         // [4][512][512]
    __shared__ _Float16 As[64][40];
    __shared__ _Float16 Bs[64][40];
    int hd = blockIdx.z;
    int m0 = blockIdx.y * 64, n0 = blockIdx.x * 64;
    const _Float16* Bp = Wh + (size_t)hd * 512 * 1024;
    const float* bias = (hd == 0) ? b0 : (hd == 1) ? b1 : (hd == 2) ? b2 : b3;
    float* C = Cout + (size_t)hd * 262144;
    int tid = threadIdx.x;
    int w = tid >> 6, lane = tid & 63, m = lane & 15, q = lane >> 4;
    int srow = tid >> 2, scol = (tid & 3) * 8;

    f4_t acc[4];
#pragma unroll
    for (int cc = 0; cc < 4; ++cc) acc[cc] = 0;

    for (int k0 = 0; k0 < 1024; k0 += 32) {
        uint4 ad = *(const uint4*)(A + (size_t)(m0 + srow) * 1024 + k0 + scol);
        uint4 bd = *(const uint4*)(Bp + (size_t)(n0 + srow) * 1024 + k0 + scol);
        __syncthreads();
        *(uint4*)(&As[srow][scol]) = ad;
        *(uint4*)(&Bs[srow][scol]) = bd;
        __syncthreads();
        h8_t a  = *(const h8_t*)(&As[w * 16 + m][q * 8]);
        h8_t bb0 = *(const h8_t*)(&Bs[ 0 + m][q * 8]);
        h8_t bb1 = *(const h8_t*)(&Bs[16 + m][q * 8]);
        h8_t bb2 = *(const h8_t*)(&Bs[32 + m][q * 8]);
        h8_t bb3 = *(const h8_t*)(&Bs[48 + m][q * 8]);
        acc[0] = __builtin_amdgcn_mfma_f32_16x16x32_f16(a, bb0, acc[0], 0, 0, 0);
        acc[1] = __builtin_amdgcn_mfma_f32_16x16x32_f16(a, bb1, acc[1], 0, 0, 0);
        acc[2] = __builtin_amdgcn_mfma_f32_16x16x32_f16(a, bb2, acc[2], 0, 0, 0);
        acc[3] = __builtin_amdgcn_mfma_f32_16x16x32_f16(a, bb3, acc[3], 0, 0, 0);
    }
#pragma unroll
    for (int r = 0; r < 4; ++r) {
        int row = m0 + w * 16 + q * 4 + r;
#pragma unroll
        for (int cc = 0; cc < 4; ++cc) {
            int ncol = n0 + cc * 16 + m;
            C[(size_t)row * 512 + ncol] = fmaxf(acc[cc][r] + bias[ncol], 0.f);
        }
    }
}

// ---------------------------------------------------------------------------
// Build U[t] = [label_head[best_arcs[t]], 1, pad0], V[t] = [label_dep[t], 1, pad0]
// ---------------------------------------------------------------------------
__global__ void uv_k(const int* __restrict__ best_arcs,
                     const float* __restrict__ label_head, const float* __restrict__ label_dep,
                     float* __restrict__ U, float* __restrict__ V) {
    int t = blockIdx.x;
    int ba = best_arcs[t];
    for (int j = threadIdx.x; j < 516; j += blockDim.x) {
        float u = (j < 512) ? label_head[(size_t)ba * 512 + j] : (j == 512 ? 1.f : 0.f);
        float v = (j < 512) ? label_dep[(size_t)t * 512 + j] : (j == 512 ? 1.f : 0.f);
        U[t * 516 + j] = u;
        V[t * 516 + j] = v;
    }
}

// ---------------------------------------------------------------------------
// U fp32 [512][516] -> Uh fp16 [512][544]
// ---------------------------------------------------------------------------
__global__ void uconv_k(const float* __restrict__ U, _Float16* __restrict__ Uh) {
    int t = blockIdx.x;
    for (int h = threadIdx.x; h < 544; h += blockDim.x)
        Uh[(size_t)t * 544 + h] = (_Float16)((h < 513) ? U[(size_t)t * 516 + h] : 0.f);
}

// ---------------------------------------------------------------------------
// MFMA label biaffine: sel[l,t] += (U[t] @ B_l[:,ktile]) . V[t,ktile]
// ---------------------------------------------------------------------------
__global__ __launch_bounds__(256) void label_mfma(
    const _Float16* __restrict__ Uh,   // [512][544]
    const _Float16* __restrict__ Bh,   // [50][576][544]
    const float* __restrict__ V,       // [512][516]
    float* __restrict__ sel) {         // [50][512]
    __shared__ _Float16 Us[64][40];
    __shared__ _Float16 Bs[64][40];
    int l = blockIdx.z;
    int t0 = blockIdx.y * 64, k0 = blockIdx.x * 64;
    int tid = threadIdx.x;
    int w = tid >> 6, lane = tid & 63, m = lane & 15, q = lane >> 4;
    const _Float16* Bl = Bh + (size_t)l * 576 * 544;
    int srow = tid >> 2, scol = (tid & 3) * 8;

    f4_t acc[4];
#pragma unroll
    for (int c = 0; c < 4; ++c) acc[c] = 0;

    for (int h0 = 0; h0 < 544; h0 += 32) {
        uint4 ud = *(const uint4*)(Uh + (size_t)(t0 + srow) * 544 + h0 + scol);
        uint4 bd = *(const uint4*)(Bl + (size_t)(k0 + srow) * 544 + h0 + scol);
        __syncthreads();
        *(uint4*)(&Us[srow][scol]) = ud;
        *(uint4*)(&Bs[srow][scol]) = bd;
        __syncthreads();
        h8_t a  = *(const h8_t*)(&Us[w * 16 + m][q * 8]);
        h8_t b0 = *(const h8_t*)(&Bs[ 0 + m][q * 8]);
        h8_t b1 = *(const h8_t*)(&Bs[16 + m][q * 8]);
        h8_t b2 = *(const h8_t*)(&Bs[32 + m][q * 8]);
        h8_t b3 = *(const h8_t*)(&Bs[48 + m][q * 8]);
        acc[0] = __builtin_amdgcn_mfma_f32_16x16x32_f16(a, b0, acc[0], 0, 0, 0);
        acc[1] = __builtin_amdgcn_mfma_f32_16x16x32_f16(a, b1, acc[1], 0, 0, 0);
        acc[2] = __builtin_amdgcn_mfma_f32_16x16x32_f16(a, b2, acc[2], 0, 0, 0);
        acc[3] = __builtin_amdgcn_mfma_f32_16x16x32_f16(a, b3, acc[3], 0, 0, 0);
    }

    float* selp = sel + (size_t)l * 512;
#pragma unroll
    for (int r = 0; r < 4; ++r) {
        int t = t0 + w * 16 + q * 4 + r;
        float vsum = 0.f;
#pragma unroll
        for (int c = 0; c < 4; ++c) {
            int k = k0 + c * 16 + m;
            float vv = (k < 513) ? V[(size_t)t * 516 + k] : 0.f;
            vsum += acc[c][r] * vv;
        }
#pragma unroll
        for (int off = 1; off < 16; off <<= 1)
            vsum += __shfl_xor(vsum, off);
        if (m == 0) atomicAdd(selp + t, vsum);
    }
}

// ---------------------------------------------------------------------------
// Row softmax in place (512x512), one WG per row
// ---------------------------------------------------------------------------
__global__ __launch_bounds__(256) void softmax_rows(float* __restrict__ Smat) {
    __shared__ float sdata[256];
    int i = blockIdx.x, tid = threadIdx.x;
    float* row = Smat + (size_t)i * 512;
    float m = -1e30f;
    for (int j = tid; j < 512; j += 256) m = fmaxf(m, row[j]);
    sdata[tid] = m; __syncthreads();
    for (int off = 128; off > 0; off >>= 1) {
        if (tid < off) sdata[tid] = fmaxf(sdata[tid], sdata[tid + off]);
        __syncthreads();
    }
    m = sdata[0]; __syncthreads();
    float ssum = 0.f;
    for (int j = tid; j < 512; j += 256) { float e = __expf(row[j] - m); row[j] = e; ssum += e; }
    sdata[tid] = ssum; __syncthreads();
    for (int off = 128; off > 0; off >>= 1) {
        if (tid < off) sdata[tid] += sdata[tid + off];
        __syncthreads();
    }
    float inv = 1.f / sdata[0];
    for (int j = tid; j < 512; j += 256) row[j] *= inv;
}

// ---------------------------------------------------------------------------
// log_softmax over l (50) for each t (512)
// ---------------------------------------------------------------------------
__global__ void lsm_k(const float* __restrict__ sel, float* __restrict__ out1) {
    int t = blockIdx.x * blockDim.x + threadIdx.x;
    if (t >= 512) return;
    float m = -1e30f;
    for (int l = 0; l < 50; ++l) m = fmaxf(m, sel[l * 512 + t]);
    float ssum = 0.f;
    for (int l = 0; l < 50; ++l) ssum += __expf(sel[l * 512 + t] - m);
    float lse = m + __logf(ssum);
    for (int l = 0; l < 50; ++l) out1[l * 512 + t] = sel[l * 512 + t] - lse;
}

// ---------------------------------------------------------------------------
extern "C" void kernel_launch(void* const* d_in, const int* in_sizes, int n_in,
                              void* d_out, int out_size, void* d_ws, size_t ws_size,
                              hipStream_t stream) {
    const int* sentence     = (const int*)d_in[0];
    const int* tags         = (const int*)d_in[1];
    const int* chars        = (const int*)d_in[2];
    const int* char_lengths = (const int*)d_in[3];
    const int* best_arcs    = (const int*)d_in[4];
    const float* word_emb   = (const float*)d_in[5];
    const float* tag_emb    = (const float*)d_in[6];
    const float* char_emb   = (const float*)d_in[7];
    const float* att_W      = (const float*)d_in[8];
    const float* att_b      = (const float*)d_in[9];
    const float* W_ih_f     = (const float*)d_in[10];
    const float* W_hh_f     = (const float*)d_in[11];
    const float* b_f        = (const float*)d_in[12];
    const float* W_ih_b     = (const float*)d_in[13];
    const float* W_hh_b     = (const float*)d_in[14];
    const float* b_b        = (const float*)d_in[15];
    const float* cW_ih      = (const float*)d_in[16];
    const float* cW_hh      = (const float*)d_in[17];
    const float* cb         = (const float*)d_in[18];
    const float* arc_dep_W  = (const float*)d_in[19];
    const float* arc_dep_b  = (const float*)d_in[20];
    const float* arc_head_W = (const float*)d_in[21];
    const float* arc_head_b = (const float*)d_in[22];
    const float* label_dep_W  = (const float*)d_in[23];
    const float* label_dep_b  = (const float*)d_in[24];
    const float* label_head_W = (const float*)d_in[25];
    const float* label_head_b = (const float*)d_in[26];
    const float* biaff_arc_W   = (const float*)d_in[27];
    const float* biaff_label_W = (const float*)d_in[28];

    float* ws = (float*)d_ws;
    float* out = (float*)d_out;

    // workspace layout (float offsets). Wh16 (fp16, 1,048,576 floats) overlays
    // [embeds,P,U,V,Uh) — lifetime-disjoint: embeds dies after prep_k (xproj);
    // hconv_k then writes Wh16; heads_mfma is its last reader; P/U/V/Uh are
    // born strictly after heads_mfma.
    const size_t o_embeds = 0;        // 204800
    const size_t o_P      = 204800;   // 262144
    const size_t o_U      = 466944;   // 264192
    const size_t o_V      = 731136;   // 264192
    const size_t o_Uh     = 995328;   // 139264  (end 1134592)
    const size_t o_Wh16   = 0;        // overlay, 1048576 floats
    const size_t o_xf     = 1134592;  // 1048576
    const size_t o_xb     = 2183168;  // 1048576
    const size_t o_lstmh  = 3231744;  // 262144 (fp16 512x1024)
    const size_t o_heads  = 3493888;  // 1048576
    const size_t o_sel    = 4542464;  // 25600
    const size_t o_hG     = 4568064;  // 2048 (1024 qwords)
    const size_t o_Bh     = 4570112;  // 7833600 (fp16 50x576x544)
    // total 12,403,712 floats = 49.6 MB (<= proven-available 50.66 MB)

    hipMemsetAsync(ws + o_hG, 0, 8192, stream);
    hipMemsetAsync(ws + o_sel, 0, 25600 * sizeof(float), stream);

    gather_k<<<512, 128, 0, stream>>>(sentence, tags, word_emb, tag_emb, ws + o_embeds);

    // prep: bconv (4050) + char (512) + xproj (512) — all independent of lstm
    prep_k<<<5074, 256, 0, stream>>>(
        biaff_label_W, (_Float16*)(ws + o_Bh),
        chars, char_lengths, char_emb, att_W, att_b, cW_ih, cW_hh, cb,
        out + 287744,
        ws + o_embeds,
        W_ih_f, b_f, ws + o_xf,
        W_ih_b, b_b, ws + o_xb);

    // head weights fp32->fp16 (embeds dead now; Wh16 overlays it)
    hconv_k<<<1024, 256, 0, stream>>>(arc_dep_W, arc_head_W, label_dep_W, label_head_W,
                                      (_Float16*)(ws + o_Wh16));

    // recurrent biLSTM, isolated on an otherwise-idle GPU
    lstm_k<<<32, 256, 0, stream>>>(W_hh_f, W_hh_b, ws + o_xf, ws + o_xb,
                                   (_Float16*)(ws + o_lstmh),
                                   (unsigned long long*)(ws + o_hG));

    heads_mfma<<<dim3(8, 8, 4), 256, 0, stream>>>(
        (const _Float16*)(ws + o_lstmh), (const _Float16*)(ws + o_Wh16),
        arc_dep_b, arc_head_b, label_dep_b, label_head_b, ws + o_heads);

    uv_k<<<512, 128, 0, stream>>>(best_arcs, ws + o_heads + 786432, ws + o_heads + 524288,
                                  ws + o_U, ws + o_V);

    // P = arc_head_a @ biaff_arc_W^T (ones column folded as bias)
    gemm_abT<<<dim3(8, 8), 256, 0, stream>>>(ws + o_heads + 262144, 512, biaff_arc_W, 513,
                                             biaff_arc_W + 512, 513,
                                             ws + o_P, 512, 512, 512, 512, 0, 0);
    // S = P @ arc_dep^T -> out0, then row-softmax in place
    gemm_abT<<<dim3(8, 8), 256, 0, stream>>>(ws + o_P, 512, ws + o_heads + 0, 512, nullptr, 0,
                                             out, 512, 512, 512, 512, 0, 0);
    softmax_rows<<<512, 256, 0, stream>>>(out);

    uconv_k<<<512, 64, 0, stream>>>(ws + o_U, (_Float16*)(ws + o_Uh));
    label_mfma<<<dim3(9, 8, 50), 256, 0, stream>>>(
        (const _Float16*)(ws + o_Uh), (const _Float16*)(ws + o_Bh),
        ws + o_V, ws + o_sel);
    lsm_k<<<2, 256, 0, stream>>>(ws + o_sel, out + 262144);
}

// Round 7
// 1327.264 us; speedup vs baseline: 1.5249x; 1.5249x over previous
//
#include <hip/hip_runtime.h>
#include <hip/hip_fp16.h>

// ---------------------------------------------------------------------------
// Problem constants
//   S=512 tokens, WD=300, TD=100, CE=20, CH=20, H=512, LAB=50, MAXW=16
// Outputs: arc_scores (512x512) | label_scores (50x512) | char_embeds (20x512)
// ---------------------------------------------------------------------------

static __device__ __forceinline__ float sigm(float x) { return 1.f / (1.f + __expf(-x)); }
static __device__ __forceinline__ float ftanh(float x) {
    x = fminf(15.f, fmaxf(-15.f, x));
    float e = __expf(2.f * x);
    return (e - 1.f) / (e + 1.f);
}

typedef _Float16 h2_t __attribute__((ext_vector_type(2)));
typedef _Float16 h8_t __attribute__((ext_vector_type(8)));
typedef float f4_t __attribute__((ext_vector_type(4)));
union U32H2 { unsigned u; h2_t h; unsigned short s[2]; };

static __device__ __forceinline__ float dot2f(unsigned wa, unsigned hb, float c) {
#if __has_builtin(__builtin_amdgcn_fdot2)
    U32H2 a, b; a.u = wa; b.u = hb;
    return __builtin_amdgcn_fdot2(a.h, b.h, c, false);
#else
    U32H2 a, b; a.u = wa; b.u = hb;
    return c + (float)a.h[0] * (float)b.h[0] + (float)a.h[1] * (float)b.h[1];
#endif
}
static __device__ __forceinline__ unsigned short f2h16(float x) {
    return __half_as_ushort(__float2half(x));
}

// ---------------------------------------------------------------------------
// Embedding gather
// ---------------------------------------------------------------------------
__global__ void gather_k(const int* __restrict__ sentence, const int* __restrict__ tags,
                         const float* __restrict__ word_emb, const float* __restrict__ tag_emb,
                         float* __restrict__ embeds) {
    int t = blockIdx.x;
    int w = sentence[t], tg = tags[t];
    for (int j = threadIdx.x; j < 400; j += blockDim.x) {
        float v = (j < 300) ? word_emb[w * 300 + j] : tag_emb[tg * 100 + (j - 300)];
        embeds[t * 400 + j] = v;
    }
}

// ---------------------------------------------------------------------------
// fp32 GEMM tile body on caller-provided LDS (used by prep_k xproj role)
// ---------------------------------------------------------------------------
static __device__ __forceinline__ void gemm_body_s(
    float* smemf, const float* __restrict__ A, int lda,
    const float* __restrict__ B, int ldb,
    const float* __restrict__ bias, int bias_stride,
    float* __restrict__ C, int ldc, int M, int K, int revA, int doRelu,
    int bm, int bn) {
    typedef float Row65[65];
    Row65* As = (Row65*)smemf;
    Row65* Bs = (Row65*)(smemf + 16 * 65);
    int tx = threadIdx.x & 15, ty = threadIdx.x >> 4;
    float acc[4][4] = {};
    for (int k0 = 0; k0 < K; k0 += 16) {
#pragma unroll
        for (int i = 0; i < 4; ++i) {
            int e = threadIdx.x + i * 256;
            int m = e >> 4, kk = e & 15;
            int row = bm + m; if (revA) row = M - 1 - row;
            As[kk][m] = A[(size_t)row * lda + k0 + kk];
            Bs[kk][m] = B[(size_t)(bn + m) * ldb + k0 + kk];
        }
        __syncthreads();
#pragma unroll
        for (int kk = 0; kk < 16; ++kk) {
            float a0 = As[kk][ty * 4 + 0], a1 = As[kk][ty * 4 + 1];
            float a2 = As[kk][ty * 4 + 2], a3 = As[kk][ty * 4 + 3];
            float b0 = Bs[kk][tx * 4 + 0], b1 = Bs[kk][tx * 4 + 1];
            float b2 = Bs[kk][tx * 4 + 2], b3 = Bs[kk][tx * 4 + 3];
            acc[0][0] += a0 * b0; acc[0][1] += a0 * b1; acc[0][2] += a0 * b2; acc[0][3] += a0 * b3;
            acc[1][0] += a1 * b0; acc[1][1] += a1 * b1; acc[1][2] += a1 * b2; acc[1][3] += a1 * b3;
            acc[2][0] += a2 * b0; acc[2][1] += a2 * b1; acc[2][2] += a2 * b2; acc[2][3] += a2 * b3;
            acc[3][0] += a3 * b0; acc[3][1] += a3 * b1; acc[3][2] += a3 * b2; acc[3][3] += a3 * b3;
        }
        __syncthreads();
    }
#pragma unroll
    for (int i = 0; i < 4; ++i) {
#pragma unroll
        for (int j = 0; j < 4; ++j) {
            int n = bn + tx * 4 + j;
            float v = acc[i][j];
            if (bias) v += bias[(size_t)n * bias_stride];
            if (doRelu) v = fmaxf(v, 0.f);
            C[(size_t)(bm + ty * 4 + i) * ldc + n] = v;
        }
    }
}

// ---------------------------------------------------------------------------
// PREP dispatch (everything independent of the LSTM, runs before it):
//   [0,4050)      : biaff_label_W fp32[l][h][k] -> fp16[l][k][h] (Bh)
//   [4050,4562)   : per-word char LSTM + gram attention
//   [4562,5074)   : 2 input projections (xf/xb)
//   [5074,5586)   : biaff_arc_W fp32[n][513] -> fp16[n][544] (W16arc)
// ---------------------------------------------------------------------------
__global__ __launch_bounds__(256) void prep_k(
    const float* __restrict__ BW, _Float16* __restrict__ Bh,
    const int* __restrict__ chars, const int* __restrict__ char_lengths,
    const float* __restrict__ char_emb, const float* __restrict__ att_W,
    const float* __restrict__ att_b, const float* __restrict__ cW_ih,
    const float* __restrict__ cW_hh, const float* __restrict__ cb,
    float* __restrict__ out2,
    const float* __restrict__ embeds,
    const float* __restrict__ Wf, const float* __restrict__ bf, float* __restrict__ Cf,
    const float* __restrict__ Wb, const float* __restrict__ bb, float* __restrict__ Cb,
    const float* __restrict__ Warc, _Float16* __restrict__ W16arc) {
    __shared__ __align__(16) unsigned char smem[16384];
    int bid = blockIdx.x;
    int tid = threadIdx.x;

    if (bid < 4050) {
        // ---------------- bconv ----------------
        typedef _Float16 TsRow[68];
        TsRow* Ts = (TsRow*)smem;
        int lb = bid / 81, rem = bid % 81;
        int h0 = (rem % 9) * 64, k0 = (rem / 9) * 64;
        const float* Bl = BW + (size_t)lb * 513 * 513;
        _Float16* BhL = Bh + (size_t)lb * 576 * 544;
        int tr = tid >> 4, tc = tid & 15;
#pragma unroll
        for (int i = 0; i < 4; ++i) {
            int hl = tr + i * 16;
            int h = h0 + hl;
#pragma unroll
            for (int j = 0; j < 4; ++j) {
                int k = k0 + tc * 4 + j;
                float v = (h < 513 && k < 513) ? Bl[(size_t)h * 513 + k] : 0.f;
                Ts[hl][tc * 4 + j] = (_Float16)v;
            }
        }
        __syncthreads();
        int cr = tid >> 2, hb = (tid & 3) * 16;
        int hg = h0 + hb;
        if (hg < 544) {
            __align__(16) _Float16 tmp[16];
#pragma unroll
            for (int j = 0; j < 16; ++j) tmp[j] = Ts[hb + j][cr];
            uint4* dst = (uint4*)(BhL + (size_t)(k0 + cr) * 544 + hg);
            dst[0] = ((const uint4*)tmp)[0];
            dst[1] = ((const uint4*)tmp)[1];
        }
    } else if (bid < 4050 + 512) {
        // ---------------- char LSTM + gram attention ----------------
        float* Wih = (float*)smem;
        float* Whh2 = Wih + 1600;
        float* cbs = Whh2 + 1600;
        float* attsh = cbs + 80;
        float* xsh = attsh + 20;
        float* hsh = xsh + 20;
        float* prodsh = hsh + 20;
        int wd = bid - 4050;
        for (int i = tid; i < 1600; i += 256) { Wih[i] = cW_ih[i]; Whh2[i] = cW_hh[i]; }
        for (int i = tid; i < 80; i += 256) cbs[i] = cb[i];
        if (tid < 20) { attsh[tid] = att_W[tid]; hsh[tid] = 0.f; }
        __syncthreads();

        int L = char_lengths[wd];
        float c = 0.f, accj = 0.f;
        for (int t = 0; t < 16; ++t) {
            if (tid < 20) xsh[tid] = char_emb[(size_t)chars[wd * 16 + t] * 20 + tid];
            __syncthreads();
            float hn = 0.f;
            if (tid < 20) {
                float z[4];
#pragma unroll
                for (int q = 0; q < 4; ++q) {
                    int rr = q * 20 + tid;
                    float sacc = cbs[rr];
                    for (int d = 0; d < 20; ++d)
                        sacc += Wih[rr * 20 + d] * xsh[d] + Whh2[rr * 20 + d] * hsh[d];
                    z[q] = sacc;
                }
                c = sigm(z[1]) * c + sigm(z[0]) * ftanh(z[2]);
                hn = sigm(z[3]) * ftanh(c);
            }
            __syncthreads();
            if (tid < 20) { hsh[tid] = hn; prodsh[tid] = hn * attsh[tid]; }
            __syncthreads();
            if (tid < 20 && t < L) {
                float st = 0.f;
                for (int k = 0; k < 20; ++k) st += prodsh[k];
                accj += hn * st;
            }
            __syncthreads();
        }
        if (tid < 20) out2[tid * 512 + wd] = accj + att_b[0];
    } else if (bid < 4050 + 512 + 512) {
        // ---------------- xproj ----------------
        int idx = bid - (4050 + 512);
        int z = idx >> 8, rem = idx & 255;
        int bn = (rem & 31) * 64;
        int bm = (rem >> 5) * 64;
        const float* W = z ? Wb : Wf;
        const float* bias = z ? bb : bf;
        float* C = z ? Cb : Cf;
        gemm_body_s((float*)smem, embeds, 400, W, 400, bias, 1, C, 2048,
                    512, 400, z, 0, bm, bn);
    } else {
        // ---------------- warc conv: [512][513] fp32 -> [512][544] fp16 ----------
        int t = bid - (4050 + 512 + 512);
        for (int j = tid; j < 544; j += 256)
            W16arc[(size_t)t * 544 + j] = (_Float16)((j < 513) ? Warc[(size_t)t * 513 + j] : 0.f);
    }
}

// ---------------------------------------------------------------------------
// hconv: 4 head weight matrices fp32 -> fp16
// ---------------------------------------------------------------------------
__global__ void hconv_k(const float* __restrict__ hw0, const float* __restrict__ hw1,
                        const float* __restrict__ hw2, const float* __restrict__ hw3,
                        _Float16* __restrict__ Wh16) {
    size_t e0 = ((size_t)blockIdx.x * 256 + threadIdx.x) * 8;
    int mat = (int)(e0 >> 19);
    size_t off = e0 & 524287;
    const float* src = (mat == 0 ? hw0 : mat == 1 ? hw1 : mat == 2 ? hw2 : hw3) + off;
    float4 f0 = ((const float4*)src)[0];
    float4 f1 = ((const float4*)src)[1];
    __align__(16) _Float16 hv[8];
    hv[0] = (_Float16)f0.x; hv[1] = (_Float16)f0.y;
    hv[2] = (_Float16)f0.z; hv[3] = (_Float16)f0.w;
    hv[4] = (_Float16)f1.x; hv[5] = (_Float16)f1.y;
    hv[6] = (_Float16)f1.z; hv[7] = (_Float16)f1.w;
    *(uint4*)(Wh16 + e0) = *(const uint4*)hv;
}

// ---------------------------------------------------------------------------
// Recurrent biLSTM — r4 structure VERBATIM (measured optimum 932 us):
// per-thread single-qword poll, intra-wave shfl h-distribution, one barrier,
// LDS partial-reduce ping-pong, 32-lane gate tail. Only change vs r4: output
// stored as fp16 for heads_mfma.
// ---------------------------------------------------------------------------
__global__ __launch_bounds__(256) void lstm_k(
    const float* __restrict__ W_hh_f, const float* __restrict__ W_hh_b,
    const float* __restrict__ xpf, const float* __restrict__ xpb,
    _Float16* __restrict__ lstmh, unsigned long long* hq) {
    int wg = blockIdx.x;
    int dir = wg >> 4, s = wg & 15;
    int tid = threadIdx.x;
    int wv = tid >> 6;
    int lane = tid & 63;
    int g = tid & 31, p = tid >> 5;
    const float* Whh = dir ? W_hh_b : W_hh_f;
    const float* xp = dir ? xpb : xpf;

    __shared__ float red[2][1024];

    unsigned Wreg[4][32];
#pragma unroll
    for (int q = 0; q < 4; ++q) {
        int gr = q * 512 + s * 32 + g;
        const float* wrow = Whh + (size_t)gr * 512 + p * 64;
#pragma unroll
        for (int u = 0; u < 32; ++u) {
            unsigned lo = f2h16(wrow[2 * u]);
            unsigned hi = f2h16(wrow[2 * u + 1]);
            Wreg[q][u] = lo | (hi << 16);
        }
    }

    float c = 0.f;
    unsigned long long* hbase = hq + dir * 512;
    int qidx = wv * 64 + lane;

    for (int t = 0; t < 512; ++t) {
        float x0 = 0.f, x1 = 0.f, x2 = 0.f, x3 = 0.f;
        if (tid < 32) {
            const float* x = xp + (size_t)t * 2048;
            int col = s * 32 + tid;
            x0 = x[col]; x1 = x[512 + col]; x2 = x[1024 + col]; x3 = x[1536 + col];
        }

        unsigned long long* hin = hbase + (t & 1) * 256;
        unsigned tag = (unsigned)t & 0xffffu;
        unsigned long long v = __hip_atomic_load(hin + qidx, __ATOMIC_RELAXED,
                                                 __HIP_MEMORY_SCOPE_AGENT);
        while ((((unsigned)(v >> 16)) & 0xffffu) != tag || ((unsigned)(v >> 48)) != tag)
            v = __hip_atomic_load(hin + qidx, __ATOMIC_RELAXED, __HIP_MEMORY_SCOPE_AGENT);
        unsigned hw = (unsigned)(v & 0xffffu) | (((unsigned)((v >> 32) & 0xffffu)) << 16);

        float a0 = 0.f, a1 = 0.f, a2 = 0.f, a3 = 0.f;
        int half_base = lane & 32;
#pragma unroll
        for (int u = 0; u < 32; ++u) {
            unsigned hwu = (unsigned)__shfl((int)hw, half_base + u);
            a0 = dot2f(Wreg[0][u], hwu, a0);
            a1 = dot2f(Wreg[1][u], hwu, a1);
            a2 = dot2f(Wreg[2][u], hwu, a2);
            a3 = dot2f(Wreg[3][u], hwu, a3);
        }
        float* r = &red[t & 1][p * 128 + g * 4];
        r[0] = a0; r[1] = a1; r[2] = a2; r[3] = a3;
        __syncthreads();

        if (tid < 32) {
            float z0 = 0.f, z1 = 0.f, z2 = 0.f, z3 = 0.f;
            const float* rb = red[t & 1];
#pragma unroll
            for (int pp = 0; pp < 8; ++pp) {
                const float* rr = rb + pp * 128 + tid * 4;
                z0 += rr[0]; z1 += rr[1]; z2 += rr[2]; z3 += rr[3];
            }
            z0 += x0; z1 += x1; z2 += x2; z3 += x3;
            c = sigm(z1) * c + sigm(z0) * ftanh(z2);
            float hn = sigm(z3) * ftanh(c);
            int col = s * 32 + tid;
            int row = dir ? (511 - t) : t;
            lstmh[(size_t)row * 1024 + dir * 512 + col] = (_Float16)hn;

            unsigned tw = (unsigned)f2h16(hn) | (((unsigned)(t + 1) & 0xffffu) << 16);
            unsigned other = (unsigned)__shfl_down((int)tw, 1);
            if ((tid & 1) == 0) {
                unsigned long long qv = (unsigned long long)tw |
                                        ((unsigned long long)other << 32);
                __hip_atomic_store(hbase + ((t + 1) & 1) * 256 + (col >> 1), qv,
                                   __ATOMIC_RELAXED, __HIP_MEMORY_SCOPE_AGENT);
            }
        }
    }
}

// ---------------------------------------------------------------------------
// Heads MFMA: z[hd] = relu(lstmh @ Wh16[hd]^T + bias[hd]), M=N=512, K=1024.
// Outputs: hd0 -> AD16 fp16[512][512]; hd1 -> AH16 fp16[512][544] (+ones col);
//          hd2 -> LD fp32[512][512];   hd3 -> LH16 fp16[512][544] (+ones col)
// ---------------------------------------------------------------------------
__global__ __launch_bounds__(256) void heads_mfma(
    const _Float16* __restrict__ A, const _Float16* __restrict__ Wh,
    const float* __restrict__ b0, const float* __restrict__ b1,
    const float* __restrict__ b2, const float* __restrict__ b3,
    _Float16* __restrict__ AD16, _Float16* __restrict__ AH16,
    float* __restrict__ LD, _Float16* __restrict__ LH16) {
    __shared__ _Float16 As[64][40];
    __shared__ _Float16 Bs[64][40];
    int hd = blockIdx.z;
    int m0 = blockIdx.y * 64, n0 = blockIdx.x * 64;
    const _Float16* Bp = Wh + (size_t)hd * 512 * 1024;
    const float* bias = (hd == 0) ? b0 : (hd == 1) ? b1 : (hd == 2) ? b2 : b3;
    int tid = threadIdx.x;
    int w = tid >> 6, lane = tid & 63, m = lane & 15, q = lane >> 4;
    int srow = tid >> 2, scol = (tid & 3) * 8;

    f4_t acc[4];
#pragma unroll
    for (int cc = 0; cc < 4; ++cc) acc[cc] = 0;

    for (int k0 = 0; k0 < 1024; k0 += 32) {
        uint4 ad = *(const uint4*)(A + (size_t)(m0 + srow) * 1024 + k0 + scol);
        uint4 bd = *(const uint4*)(Bp + (size_t)(n0 + srow) * 1024 + k0 + scol);
        __syncthreads();
        *(uint4*)(&As[srow][scol]) = ad;
        *(uint4*)(&Bs[srow][scol]) = bd;
        __syncthreads();
        h8_t a  = *(const h8_t*)(&As[w * 16 + m][q * 8]);
        h8_t bb0 = *(const h8_t*)(&Bs[ 0 + m][q * 8]);
        h8_t bb1 = *(const h8_t*)(&Bs[16 + m][q * 8]);
        h8_t bb2 = *(const h8_t*)(&Bs[32 + m][q * 8]);
        h8_t bb3 = *(const h8_t*)(&Bs[48 + m][q * 8]);
        acc[0] = __builtin_amdgcn_mfma_f32_16x16x32_f16(a, bb0, acc[0], 0, 0, 0);
        acc[1] = __builtin_amdgcn_mfma_f32_16x16x32_f16(a, bb1, acc[1], 0, 0, 0);
        acc[2] = __builtin_amdgcn_mfma_f32_16x16x32_f16(a, bb2, acc[2], 0, 0, 0);
        acc[3] = __builtin_amdgcn_mfma_f32_16x16x32_f16(a, bb3, acc[3], 0, 0, 0);
    }
#pragma unroll
    for (int r = 0; r < 4; ++r) {
        int row = m0 + w * 16 + q * 4 + r;
#pragma unroll
        for (int cc = 0; cc < 4; ++cc) {
            int ncol = n0 + cc * 16 + m;
            float v = fmaxf(acc[cc][r] + bias[ncol], 0.f);
            if (hd == 2)      LD[(size_t)row * 512 + ncol] = v;
            else if (hd == 0) AD16[(size_t)row * 512 + ncol] = (_Float16)v;
            else {
                _Float16* dst = (hd == 1) ? AH16 : LH16;
                dst[(size_t)row * 544 + ncol] = (_Float16)v;
            }
        }
    }
    // ones + zero-pad columns (512..543) for the 544-stride fp16 heads
    if ((hd == 1 || hd == 3) && blockIdx.x == 7 && tid < 64) {
        _Float16* dst = (hd == 1) ? AH16 : LH16;
        int row = m0 + tid;
        dst[(size_t)row * 544 + 512] = (_Float16)1.f;
        for (int j = 513; j < 544; ++j) dst[(size_t)row * 544 + j] = (_Float16)0.f;
    }
}

// ---------------------------------------------------------------------------
// uv2: Uh[t] = LH16[best_arcs[t]] (fp16 row copy, 544), V[t] = [LD[t],1,pad0]
// ---------------------------------------------------------------------------
__global__ void uv2_k(const int* __restrict__ best_arcs,
                      const _Float16* __restrict__ LH16, const float* __restrict__ LD,
                      _Float16* __restrict__ Uh, float* __restrict__ V) {
    int t = blockIdx.x;
    int ba = best_arcs[t];
    const unsigned* src = (const unsigned*)(LH16 + (size_t)ba * 544);
    unsigned* dst = (unsigned*)(Uh + (size_t)t * 544);
    for (int j = threadIdx.x; j < 272; j += blockDim.x) dst[j] = src[j];
    for (int j = threadIdx.x; j < 516; j += blockDim.x)
        V[t * 516 + j] = (j < 512) ? LD[(size_t)t * 512 + j] : (j == 512 ? 1.f : 0.f);
}

// ---------------------------------------------------------------------------
// Generic fp16 MFMA GEMM: C[64x64 tile] = A[M,K]@B[N,K]^T, ldc=512.
// C16 != null -> fp16 out; else fp32 out to C32.
// ---------------------------------------------------------------------------
__global__ __launch_bounds__(256) void gemm16_mfma(
    const _Float16* __restrict__ A, int lda,
    const _Float16* __restrict__ B, int ldb, int K,
    _Float16* __restrict__ C16, float* __restrict__ C32) {
    __shared__ _Float16 As[64][40];
    __shared__ _Float16 Bs[64][40];
    int m0 = blockIdx.y * 64, n0 = blockIdx.x * 64;
    int tid = threadIdx.x;
    int w = tid >> 6, lane = tid & 63, m = lane & 15, q = lane >> 4;
    int srow = tid >> 2, scol = (tid & 3) * 8;

    f4_t acc[4];
#pragma unroll
    for (int cc = 0; cc < 4; ++cc) acc[cc] = 0;

    for (int k0 = 0; k0 < K; k0 += 32) {
        uint4 ad = *(const uint4*)(A + (size_t)(m0 + srow) * lda + k0 + scol);
        uint4 bd = *(const uint4*)(B + (size_t)(n0 + srow) * ldb + k0 + scol);
        __syncthreads();
        *(uint4*)(&As[srow][scol]) = ad;
        *(uint4*)(&Bs[srow][scol]) = bd;
        __syncthreads();
        h8_t a  = *(const h8_t*)(&As[w * 16 + m][q * 8]);
        h8_t b0 = *(const h8_t*)(&Bs[ 0 + m][q * 8]);
        h8_t b1 = *(const h8_t*)(&Bs[16 + m][q * 8]);
        h8_t b2 = *(const h8_t*)(&Bs[32 + m][q * 8]);
        h8_t b3 = *(const h8_t*)(&Bs[48 + m][q * 8]);
        acc[0] = __builtin_amdgcn_mfma_f32_16x16x32_f16(a, b0, acc[0], 0, 0, 0);
        acc[1] = __builtin_amdgcn_mfma_f32_16x16x32_f16(a, b1, acc[1], 0, 0, 0);
        acc[2] = __builtin_amdgcn_mfma_f32_16x16x32_f16(a, b2, acc[2], 0, 0, 0);
        acc[3] = __builtin_amdgcn_mfma_f32_16x16x32_f16(a, b3, acc[3], 0, 0, 0);
    }
#pragma unroll
    for (int r = 0; r < 4; ++r) {
        int row = m0 + w * 16 + q * 4 + r;
#pragma unroll
        for (int cc = 0; cc < 4; ++cc) {
            int ncol = n0 + cc * 16 + m;
            if (C16) C16[(size_t)row * 512 + ncol] = (_Float16)acc[cc][r];
            else     C32[(size_t)row * 512 + ncol] = acc[cc][r];
        }
    }
}

// ---------------------------------------------------------------------------
// MFMA label biaffine: sel[l,t] += (U[t] @ B_l[:,ktile]) . V[t,ktile]
// ---------------------------------------------------------------------------
__global__ __launch_bounds__(256) void label_mfma(
    const _Float16* __restrict__ Uh, const _Float16* __restrict__ Bh,
    const float* __restrict__ V, float* __restrict__ sel) {
    __shared__ _Float16 Us[64][40];
    __shared__ _Float16 Bs[64][40];
    int l = blockIdx.z;
    int t0 = blockIdx.y * 64, k0 = blockIdx.x * 64;
    int tid = threadIdx.x;
    int w = tid >> 6, lane = tid & 63, m = lane & 15, q = lane >> 4;
    const _Float16* Bl = Bh + (size_t)l * 576 * 544;
    int srow = tid >> 2, scol = (tid & 3) * 8;

    f4_t acc[4];
#pragma unroll
    for (int c = 0; c < 4; ++c) acc[c] = 0;

    for (int h0 = 0; h0 < 544; h0 += 32) {
        uint4 ud = *(const uint4*)(Uh + (size_t)(t0 + srow) * 544 + h0 + scol);
        uint4 bd = *(const uint4*)(Bl + (size_t)(k0 + srow) * 544 + h0 + scol);
        __syncthreads();
        *(uint4*)(&Us[srow][scol]) = ud;
        *(uint4*)(&Bs[srow][scol]) = bd;
        __syncthreads();
        h8_t a  = *(const h8_t*)(&Us[w * 16 + m][q * 8]);
        h8_t b0 = *(const h8_t*)(&Bs[ 0 + m][q * 8]);
        h8_t b1 = *(const h8_t*)(&Bs[16 + m][q * 8]);
        h8_t b2 = *(const h8_t*)(&Bs[32 + m][q * 8]);
        h8_t b3 = *(const h8_t*)(&Bs[48 + m][q * 8]);
        acc[0] = __builtin_amdgcn_mfma_f32_16x16x32_f16(a, b0, acc[0], 0, 0, 0);
        acc[1] = __builtin_amdgcn_mfma_f32_16x16x32_f16(a, b1, acc[1], 0, 0, 0);
        acc[2] = __builtin_amdgcn_mfma_f32_16x16x32_f16(a, b2, acc[2], 0, 0, 0);
        acc[3] = __builtin_amdgcn_mfma_f32_16x16x32_f16(a, b3, acc[3], 0, 0, 0);
    }

    float* selp = sel + (size_t)l * 512;
#pragma unroll
    for (int r = 0; r < 4; ++r) {
        int t = t0 + w * 16 + q * 4 + r;
        float vsum = 0.f;
#pragma unroll
        for (int c = 0; c < 4; ++c) {
            int k = k0 + c * 16 + m;
            float vv = (k < 513) ? V[(size_t)t * 516 + k] : 0.f;
            vsum += acc[c][r] * vv;
        }
#pragma unroll
        for (int off = 1; off < 16; off <<= 1)
            vsum += __shfl_xor(vsum, off);
        if (m == 0) atomicAdd(selp + t, vsum);
    }
}

// ---------------------------------------------------------------------------
// Row softmax in place (512x512)
// ---------------------------------------------------------------------------
__global__ __launch_bounds__(256) void softmax_rows(float* __restrict__ Smat) {
    __shared__ float sdata[256];
    int i = blockIdx.x, tid = threadIdx.x;
    float* row = Smat + (size_t)i * 512;
    float m = -1e30f;
    for (int j = tid; j < 512; j += 256) m = fmaxf(m, row[j]);
    sdata[tid] = m; __syncthreads();
    for (int off = 128; off > 0; off >>= 1) {
        if (tid < off) sdata[tid] = fmaxf(sdata[tid], sdata[tid + off]);
        __syncthreads();
    }
    m = sdata[0]; __syncthreads();
    float ssum = 0.f;
    for (int j = tid; j < 512; j += 256) { float e = __expf(row[j] - m); row[j] = e; ssum += e; }
    sdata[tid] = ssum; __syncthreads();
    for (int off = 128; off > 0; off >>= 1) {
        if (tid < off) sdata[tid] += sdata[tid + off];
        __syncthreads();
    }
    float inv = 1.f / sdata[0];
    for (int j = tid; j < 512; j += 256) row[j] *= inv;
}

// ---------------------------------------------------------------------------
// log_softmax over l (50) for each t (512)
// ---------------------------------------------------------------------------
__global__ void lsm_k(const float* __restrict__ sel, float* __restrict__ out1) {
    int t = blockIdx.x * blockDim.x + threadIdx.x;
    if (t >= 512) return;
    float m = -1e30f;
    for (int l = 0; l < 50; ++l) m = fmaxf(m, sel[l * 512 + t]);
    float ssum = 0.f;
    for (int l = 0; l < 50; ++l) ssum += __expf(sel[l * 512 + t] - m);
    float lse = m + __logf(ssum);
    for (int l = 0; l < 50; ++l) out1[l * 512 + t] = sel[l * 512 + t] - lse;
}

// ---------------------------------------------------------------------------
extern "C" void kernel_launch(void* const* d_in, const int* in_sizes, int n_in,
                              void* d_out, int out_size, void* d_ws, size_t ws_size,
                              hipStream_t stream) {
    const int* sentence     = (const int*)d_in[0];
    const int* tags         = (const int*)d_in[1];
    const int* chars        = (const int*)d_in[2];
    const int* char_lengths = (const int*)d_in[3];
    const int* best_arcs    = (const int*)d_in[4];
    const float* word_emb   = (const float*)d_in[5];
    const float* tag_emb    = (const float*)d_in[6];
    const float* char_emb   = (const float*)d_in[7];
    const float* att_W      = (const float*)d_in[8];
    const float* att_b      = (const float*)d_in[9];
    const float* W_ih_f     = (const float*)d_in[10];
    const float* W_hh_f     = (const float*)d_in[11];
    const float* b_f        = (const float*)d_in[12];
    const float* W_ih_b     = (const float*)d_in[13];
    const float* W_hh_b     = (const float*)d_in[14];
    const float* b_b        = (const float*)d_in[15];
    const float* cW_ih      = (const float*)d_in[16];
    const float* cW_hh      = (const float*)d_in[17];
    const float* cb         = (const float*)d_in[18];
    const float* arc_dep_W  = (const float*)d_in[19];
    const float* arc_dep_b  = (const float*)d_in[20];
    const float* arc_head_W = (const float*)d_in[21];
    const float* arc_head_b = (const float*)d_in[22];
    const float* label_dep_W  = (const float*)d_in[23];
    const float* label_dep_b  = (const float*)d_in[24];
    const float* label_head_W = (const float*)d_in[25];
    const float* label_head_b = (const float*)d_in[26];
    const float* biaff_arc_W   = (const float*)d_in[27];
    const float* biaff_label_W = (const float*)d_in[28];

    float* ws = (float*)d_ws;
    float* out = (float*)d_out;

    // workspace layout (float offsets), ~49.6 MB total (within proven budget).
    // Wh16 overlays [0,1048576): embeds dies after prep_k; V/Uh (also in that
    // range) are born after heads_mfma, Wh16's last reader.
    const size_t o_embeds = 0;            // 204800
    const size_t o_Wh16   = 0;            // overlay, 1048576
    const size_t o_V      = 204800;       // 264192 (born after heads_mfma)
    const size_t o_Uh     = 468992;       // 139264 (fp16 512x544)
    const size_t o_xf     = 1134592;      // 1048576
    const size_t o_xb     = 2183168;      // 1048576
    const size_t o_lstmh  = 3231744;      // 262144 (fp16 512x1024)
    const size_t o_heads  = 3493888;      // 1048576 region, sub-layout:
    const size_t o_LD     = o_heads + 0;       // fp32 512x512   (262144)
    const size_t o_AD16   = o_heads + 262144;  // fp16 512x512   (131072)
    const size_t o_AH16   = o_heads + 393216;  // fp16 512x544   (139264)
    const size_t o_LH16   = o_heads + 532480;  // fp16 512x544   (139264)
    const size_t o_P16    = o_heads + 671744;  // fp16 512x512   (131072)
    const size_t o_Warc16 = o_heads + 802816;  // fp16 512x544   (139264) -> ends 942080
    const size_t o_sel    = 4542464;      // 25600
    const size_t o_hG     = 4568064;      // 2048 (1024 qwords)
    const size_t o_Bh     = 4570112;      // 7833600 (fp16 50x576x544)

    hipMemsetAsync(ws + o_hG, 0, 8192, stream);
    hipMemsetAsync(ws + o_sel, 0, 25600 * sizeof(float), stream);

    gather_k<<<512, 128, 0, stream>>>(sentence, tags, word_emb, tag_emb, ws + o_embeds);

    // prep: bconv(4050) + char(512) + xproj(512) + warc conv(512)
    prep_k<<<5586, 256, 0, stream>>>(
        biaff_label_W, (_Float16*)(ws + o_Bh),
        chars, char_lengths, char_emb, att_W, att_b, cW_ih, cW_hh, cb,
        out + 287744,
        ws + o_embeds,
        W_ih_f, b_f, ws + o_xf,
        W_ih_b, b_b, ws + o_xb,
        biaff_arc_W, (_Float16*)(ws + o_Warc16));

    hconv_k<<<1024, 256, 0, stream>>>(arc_dep_W, arc_head_W, label_dep_W, label_head_W,
                                      (_Float16*)(ws + o_Wh16));

    // recurrent biLSTM, isolated (r4 structure)
    lstm_k<<<32, 256, 0, stream>>>(W_hh_f, W_hh_b, ws + o_xf, ws + o_xb,
                                   (_Float16*)(ws + o_lstmh),
                                   (unsigned long long*)(ws + o_hG));

    heads_mfma<<<dim3(8, 8, 4), 256, 0, stream>>>(
        (const _Float16*)(ws + o_lstmh), (const _Float16*)(ws + o_Wh16),
        arc_dep_b, arc_head_b, label_dep_b, label_head_b,
        (_Float16*)(ws + o_AD16), (_Float16*)(ws + o_AH16),
        ws + o_LD, (_Float16*)(ws + o_LH16));

    uv2_k<<<512, 128, 0, stream>>>(best_arcs, (const _Float16*)(ws + o_LH16),
                                   ws + o_LD, (_Float16*)(ws + o_Uh), ws + o_V);

    // arc path: P16 = AH16 @ W16arc^T (K=544), S = P16 @ AD16^T (K=512) -> out
    gemm16_mfma<<<dim3(8, 8), 256, 0, stream>>>(
        (const _Float16*)(ws + o_AH16), 544, (const _Float16*)(ws + o_Warc16), 544, 544,
        (_Float16*)(ws + o_P16), nullptr);
    gemm16_mfma<<<dim3(8, 8), 256, 0, stream>>>(
        (const _Float16*)(ws + o_P16), 512, (const _Float16*)(ws + o_AD16), 512, 512,
        nullptr, out);
    softmax_rows<<<512, 256, 0, stream>>>(out);

    label_mfma<<<dim3(9, 8, 50), 256, 0, stream>>>(
        (const _Float16*)(ws + o_Uh), (const _Float16*)(ws + o_Bh),
        ws + o_V, ws + o_sel);
    lsm_k<<<2, 256, 0, stream>>>(ws + o_sel, out + 262144);
}